// Round 16
// baseline (918.901 us; speedup 1.0000x reference)
//
#include <hip/hip_runtime.h>
#include <hip/hip_bf16.h>

typedef _Float16 half8 __attribute__((ext_vector_type(8)));
typedef _Float16 half4 __attribute__((ext_vector_type(4)));
typedef float f32x4 __attribute__((ext_vector_type(4)));

// Geometry: D=256, H=8, A=64, M=400000 (64*6250), N=50000
// Algebra: out_g = sum_h (u_{g,h}/s_{g,h}) @ (Wv_h @ Wout_h) + bout
//          u_{g,h} = sum_{m in g} e_{m,h} * msg_m

#define MFMA16(a, b, c) __builtin_amdgcn_mfma_f32_16x16x32_f16(a, b, c, 0, 0, 0)

// ---------------- wqkT panels in FRAGMENT ORDER ----------------
__global__ void k_convert(const float* __restrict__ Wq, const float* __restrict__ Wk,
                          _Float16* __restrict__ wqkT)
{
    int gid = blockIdx.x * 256 + threadIdx.x;   // 131072
    int h = gid >> 14;
    int d = (gid >> 6) & 255;
    int a = gid & 63;
    int k0 = d >> 5, lk = (d >> 3) & 3, j = d & 7;
    int cb = a >> 4, lr = a & 15;
    int idx = ((k0 * 4 + cb) * 64 + lk * 16 + lr) * 8 + j;
    wqkT[h * 16384 + idx]       = (_Float16)Wq[gid];
    wqkT[(8 + h) * 16384 + idx] = (_Float16)Wk[gid];
}

// ---------------- CT = Wv_h @ Wout_h in FRAGMENT ORDER ----------------
__global__ void k_convC(const float* __restrict__ Wv, const float* __restrict__ Wout,
                        _Float16* __restrict__ CT)
{
    __shared__ float wv[4][64];
    int h = blockIdx.x >> 6, din0 = (blockIdx.x & 63) << 2;
    int t = threadIdx.x;
    wv[t >> 6][t & 63] = Wv[((h << 8) + din0 + (t >> 6)) * 64 + (t & 63)];
    __syncthreads();
    float s[4] = {0.f, 0.f, 0.f, 0.f};
    for (int a = 0; a < 64; ++a) {
        float wo = Wout[(h * 64 + a) * 256 + t];
        #pragma unroll
        for (int dd = 0; dd < 4; ++dd) s[dd] += wv[dd][a] * wo;
    }
    int nb = t >> 4, lr = t & 15;
    #pragma unroll
    for (int dd = 0; dd < 4; ++dd) {
        int din = din0 + dd;
        int k0 = din >> 5, lk = (din >> 3) & 3, j = din & 7;
        CT[(size_t)((nb * 8 + h) * 8 + k0) * 512 + (lk * 16 + lr) * 8 + j] = (_Float16)s[dd];
    }
}

// ---------------- counting sort ----------------
__global__ void k_hist(const int* __restrict__ index, int* __restrict__ counts, int M) {
    int m = blockIdx.x * 256 + threadIdx.x;
    if (m < M) atomicAdd(&counts[index[m]], 1);
}

__global__ __launch_bounds__(1024) void k_scan1(const int* __restrict__ counts,
                                                int* __restrict__ starts,
                                                int* __restrict__ blocktot, int N) {
    __shared__ int s[1024];
    int b = blockIdx.x, t = threadIdx.x;
    int i = b * 1024 + t;
    int x = (i < N) ? counts[i] : 0;
    s[t] = x;
    __syncthreads();
    #pragma unroll
    for (int off = 1; off < 1024; off <<= 1) {
        int v = (t >= off) ? s[t - off] : 0;
        __syncthreads();
        s[t] += v;
        __syncthreads();
    }
    if (i < N) starts[i] = s[t] - x;
    if (t == 1023) blocktot[b] = s[1023];
}

__global__ void k_scan2(const int* __restrict__ blocktot, int* __restrict__ blockoff, int NC) {
    if (threadIdx.x == 0 && blockIdx.x == 0) {
        int run = 0;
        for (int i = 0; i < NC; ++i) { blockoff[i] = run; run += blocktot[i]; }
    }
}

__global__ __launch_bounds__(1024) void k_scan3(int* __restrict__ starts,
                                                int* __restrict__ cursor,
                                                const int* __restrict__ blockoff,
                                                int N, int M) {
    int b = blockIdx.x, t = threadIdx.x;
    int i = b * 1024 + t;
    if (i < N) {
        int v = starts[i] + blockoff[b];
        starts[i] = v;
        cursor[i] = v;
    }
    if (b == 0 && t == 0) starts[N] = M;
}

__global__ void k_scatteridx(const int* __restrict__ index, int* __restrict__ cursor,
                             int* __restrict__ sorted, int* __restrict__ segsorted, int M) {
    int m = blockIdx.x * 256 + threadIdx.x;
    if (m < M) {
        int idx = index[m];
        int pos = atomicAdd(&cursor[idx], 1);
        sorted[pos] = m;
        segsorted[pos] = idx;
    }
}

// ---------------- zero u rows of block-boundary segments (64-row blocks) ---------
__global__ __launch_bounds__(256) void k_zero_bnd(const int* __restrict__ segsorted,
                                                  float* __restrict__ u, int M) {
    long r0 = (long)blockIdx.x * 64;
    int g0 = segsorted[r0];
    int g1 = segsorted[r0 + 63];
    int t = threadIdx.x;
    float4 z = {0.f, 0.f, 0.f, 0.f};
    float4* p0 = (float4*)(u + (long)g0 * 2048);
    float4* p1 = (float4*)(u + (long)g1 * 2048);
    p0[t] = z; p0[t + 256] = z;
    p1[t] = z; p1[t + 256] = z;
}

// ---------------- flush helper (nt store on interior; atomics on boundary) --------
__device__ __forceinline__ void flush_u(float* __restrict__ u, float* __restrict__ segsum,
                                        int g, int gl0, int ghi, int h, int l,
                                        f32x4 a0, float se)
{
    bool bd = (g == gl0) || (g == ghi);
    float* d0 = u + (long)g * 2048 + h * 256 + l * 4;
    if (bd) {
        atomicAdd(d0 + 0, a0[0]); atomicAdd(d0 + 1, a0[1]);
        atomicAdd(d0 + 2, a0[2]); atomicAdd(d0 + 3, a0[3]);
    } else {
        __builtin_nontemporal_store(a0, (f32x4*)d0);
    }
    if (l == 0) {
        float* ds = segsum + (long)g * 8 + h;
        if (bd) atomicAdd(ds, se); else *ds = se;
    }
}

// ---------------- fused: barrier-free scores + weighted segment-sum ----------------
// 64-row blocks, 8 waves. Score: wave w -> row-half rh=w&1 (32 rows, 2 tiles),
// heads {w>>1, (w>>1)+4}. Register-light r14 inner (6 f32x4 live) -> VGPR ~64;
// LDS ~36 KB -> 4 blocks/CU -> up to 32 waves/CU for latency hiding.
__global__ __launch_bounds__(512) void k_score_wsum(
    const float* __restrict__ msg, const int* __restrict__ sorted,
    const int* __restrict__ segsorted, const _Float16* __restrict__ wqkT,
    float* __restrict__ u, float* __restrict__ segsum, int M)
{
    __shared__ __align__(16) _Float16 At[64 * 256];    // 32 KB, XOR-swz row-major
    __shared__ float e_lds[64][9];                     // 2.3 KB
    __shared__ int s_id[64];
    __shared__ int s_sg[64];
    char* ldsA = (char*)At;
    const int t = threadIdx.x;

    // bijective XCD-chunked swizzle
    int nwg = gridDim.x;
    int qc = nwg >> 3, rc = nwg & 7;
    int xcd = blockIdx.x & 7, ofs = blockIdx.x >> 3;
    int blk = ((xcd < rc) ? xcd * (qc + 1) : rc * (qc + 1) + (xcd - rc) * qc) + ofs;
    const long m0 = (long)blk * 64;

    if (t < 64) {
        s_id[t] = sorted[m0 + t];
        s_sg[t] = segsorted[m0 + t];
    }
    __syncthreads();

    // stage A: gathered 64x256 f32 -> f16 LDS (swz); nt-loads keep wqkT in L2
    const f32x4* msgf4 = (const f32x4*)msg;
    #pragma unroll
    for (int it = 0; it < 8; ++it) {
        int e4 = it * 512 + t;
        int row = e4 >> 6, c4 = e4 & 63;
        f32x4 v = __builtin_nontemporal_load(msgf4 + (long)s_id[row] * 64 + c4);
        half4 hv = {(_Float16)v[0], (_Float16)v[1], (_Float16)v[2], (_Float16)v[3]};
        int bb = ((row << 9) + (c4 << 3)) ^ ((row & 7) << 4);
        *(half4*)(ldsA + bb) = hv;
    }
    __syncthreads();

    const int w = t >> 6, l = t & 63, lr = l & 15, lk = l >> 4;
    const int rh = w & 1;     // row half: rows rh*32 .. rh*32+31
    const int hp = w >> 1;    // heads hp, hp+4
    const f32x4 zero = {0.f, 0.f, 0.f, 0.f};

    #pragma unroll 1
    for (int hh = 0; hh < 2; ++hh) {
        const int h = hp + hh * 4;
        const _Float16* wq = wqkT + (size_t)h * 16384;
        const _Float16* wk = wqkT + (size_t)(8 + h) * 16384;

        const int r0 = rh * 32 + lr;
        const int r1 = r0 + 16;
        f32x4 pq0 = zero, pq1 = zero;
        #pragma unroll 1
        for (int cb = 0; cb < 4; ++cb) {
            f32x4 aq0 = zero, aq1 = zero, ak0 = zero, ak1 = zero;
            #pragma unroll
            for (int k0 = 0; k0 < 8; ++k0) {
                int c = k0 * 64 + lk * 16;
                half8 a0 = *(const half8*)(ldsA + (((r0 << 9) + c) ^ ((r0 & 7) << 4)));
                half8 a1 = *(const half8*)(ldsA + (((r1 << 9) + c) ^ ((r1 & 7) << 4)));
                half8 bq = *(const half8*)(wq + ((k0 * 4 + cb) * 64 + l) * 8);
                half8 bk = *(const half8*)(wk + ((k0 * 4 + cb) * 64 + l) * 8);
                aq0 = MFMA16(a0, bq, aq0);
                ak0 = MFMA16(a0, bk, ak0);
                aq1 = MFMA16(a1, bq, aq1);
                ak1 = MFMA16(a1, bk, ak1);
            }
            pq0 += aq0 * ak0;
            pq1 += aq1 * ak1;
        }
        // butterfly over the 16-lane col group
        #pragma unroll
        for (int off = 1; off < 16; off <<= 1) {
            pq0[0] += __shfl_xor(pq0[0], off); pq0[1] += __shfl_xor(pq0[1], off);
            pq0[2] += __shfl_xor(pq0[2], off); pq0[3] += __shfl_xor(pq0[3], off);
            pq1[0] += __shfl_xor(pq1[0], off); pq1[1] += __shfl_xor(pq1[1], off);
            pq1[2] += __shfl_xor(pq1[2], off); pq1[3] += __shfl_xor(pq1[3], off);
        }
        if (lr == 0) {
            int rb = rh * 32 + lk * 4;
            #pragma unroll
            for (int j = 0; j < 4; ++j) {
                float s0 = pq0[j];
                s0 = (s0 >= 0.f) ? s0 : 0.2f * s0;
                e_lds[rb + j][h] = __expf(s0);         // |s|<~50 << 88: f32-safe
                float s1 = pq1[j];
                s1 = (s1 >= 0.f) ? s1 : 0.2f * s1;
                e_lds[rb + 16 + j][h] = __expf(s1);
            }
        }
    }
    __syncthreads();

    // ---- weighted segment-sum: wave w -> head w; lane owns 4 msg cols ----
    const int gl0 = s_sg[0], ghi = s_sg[63];
    f32x4 a0 = zero;
    float se = 0.f;
    int cur = gl0;

    #pragma unroll 4
    for (int row = 0; row < 64; ++row) {
        int sg = s_sg[row];
        if (sg != cur) {                 // wave-uniform branch
            flush_u(u, segsum, cur, gl0, ghi, w, l, a0, se);
            cur = sg; a0 = zero; se = 0.f;
        }
        int bb = ((row << 9) + (l << 3)) ^ ((row & 7) << 4);
        half4 mv = *(const half4*)(ldsA + bb);
        float e = e_lds[row][w];
        a0[0] += e * (float)mv[0];
        a0[1] += e * (float)mv[1];
        a0[2] += e * (float)mv[2];
        a0[3] += e * (float)mv[3];
        se += e;
    }
    flush_u(u, segsum, cur, gl0, ghi, w, l, a0, se);
}

// ---------------- out: barrier-free, LDS-free, 32 rows/wave ----------------
__global__ __launch_bounds__(256, 2) void k_out3(
    const float* __restrict__ u, const float* __restrict__ segsum,
    const _Float16* __restrict__ CT, const float* __restrict__ bout,
    float* __restrict__ out, int N)
{
    const int t = threadIdx.x;
    const int w = t >> 6, l = t & 63, lr = l & 15, lk = l >> 4;
    const long r0 = ((long)blockIdx.x * 4 + w) * 32;
    if (r0 >= N) return;            // no barriers: safe early exit

    const f32x4 zero = {0.f, 0.f, 0.f, 0.f};
    f32x4 ac0[16], ac1[16];
    #pragma unroll
    for (int nb = 0; nb < 16; ++nb) { ac0[nb] = zero; ac1[nb] = zero; }

    long rlo = r0 + lr;      if (rlo > N - 1) rlo = N - 1;   // clamp reads
    long rhi = r0 + 16 + lr; if (rhi > N - 1) rhi = N - 1;
    const float* ulo = u + rlo * 2048;
    const float* uhi = u + rhi * 2048;
    const float* sslo = segsum + rlo * 8;
    const float* sshi = segsum + rhi * 8;

    #pragma unroll 1
    for (int kc = 0; kc < 8; ++kc) {
        float s0 = sslo[kc];
        float i0 = (s0 > 0.f) ? 1.f / s0 : 0.f;
        float s1 = sshi[kc];
        float i1 = (s1 > 0.f) ? 1.f / s1 : 0.f;
        #pragma unroll
        for (int k0 = 0; k0 < 8; ++k0) {
            const f32x4* p0 = (const f32x4*)(ulo + kc * 256 + k0 * 32 + lk * 8);
            const f32x4* p1 = (const f32x4*)(uhi + kc * 256 + k0 * 32 + lk * 8);
            f32x4 ua = __builtin_nontemporal_load(p0);
            f32x4 ub = __builtin_nontemporal_load(p0 + 1);
            f32x4 uc = __builtin_nontemporal_load(p1);
            f32x4 ud = __builtin_nontemporal_load(p1 + 1);
            half8 alo = {(_Float16)(ua[0] * i0), (_Float16)(ua[1] * i0),
                         (_Float16)(ua[2] * i0), (_Float16)(ua[3] * i0),
                         (_Float16)(ub[0] * i0), (_Float16)(ub[1] * i0),
                         (_Float16)(ub[2] * i0), (_Float16)(ub[3] * i0)};
            half8 ahi = {(_Float16)(uc[0] * i1), (_Float16)(uc[1] * i1),
                         (_Float16)(uc[2] * i1), (_Float16)(uc[3] * i1),
                         (_Float16)(ud[0] * i1), (_Float16)(ud[1] * i1),
                         (_Float16)(ud[2] * i1), (_Float16)(ud[3] * i1)};
            #pragma unroll
            for (int nb = 0; nb < 16; ++nb) {
                half8 b = *(const half8*)(CT + (size_t)((nb * 8 + kc) * 8 + k0) * 512 + l * 8);
                ac0[nb] = MFMA16(alo, b, ac0[nb]);
                ac1[nb] = MFMA16(ahi, b, ac1[nb]);
            }
        }
    }

    #pragma unroll
    for (int nb = 0; nb < 16; ++nb) {
        int col = nb * 16 + lr;
        float bb = bout[col];
        #pragma unroll
        for (int j = 0; j < 4; ++j) {
            long row = r0 + lk * 4 + j;
            if (row < N) out[row * 256 + col] = ac0[nb][j] + bb;
            long row2 = r0 + 16 + lk * 4 + j;
            if (row2 < N) out[row2 * 256 + col] = ac1[nb][j] + bb;
        }
    }
}

extern "C" void kernel_launch(void* const* d_in, const int* in_sizes, int n_in,
                              void* d_out, int out_size, void* d_ws, size_t ws_size,
                              hipStream_t stream)
{
    const float* msg   = (const float*)d_in[0];
    const int*   index = (const int*)d_in[1];
    const float* Wq    = (const float*)d_in[4];
    const float* Wk    = (const float*)d_in[5];
    const float* Wv    = (const float*)d_in[6];
    const float* Wout  = (const float*)d_in[7];
    const float* bout  = (const float*)d_in[8];
    float* out = (float*)d_out;

    const int M = in_sizes[0] / 256;   // 400000
    const int N = out_size / 256;      // 50000
    const int NC = (N + 1023) / 1024;  // 49 scan chunks

    char* ws = (char*)d_ws;
    _Float16* wqkT = (_Float16*)(ws);              // 524288 B
    _Float16* CT   = (_Float16*)(ws + 524288);     // 1048576 B
    size_t o2 = 1572864;
    float* segsum = (float*)(ws + o2);                         // N*32
    int* counts   = (int*)(ws + o2 + (size_t)N * 32);          // N*4
    size_t uoff   = (o2 + (size_t)N * 36 + 255) & ~(size_t)255;
    float* u      = (float*)(ws + uoff);                       // N*8192
    size_t p2     = uoff + (size_t)N * 8192;
    int* cursor    = (int*)(ws + p2);                          // N*4
    int* starts    = (int*)(ws + p2 + (size_t)N * 4);          // (N+1)*4
    char* p3       = ws + p2 + (((size_t)N * 8 + 4 + 63) & ~(size_t)63);
    int* sorted    = (int*)(p3);                               // M*4
    int* segsorted = (int*)(p3 + (size_t)M * 4);               // M*4
    int* blocktot  = (int*)(p3 + (size_t)M * 8);               // 256 B
    int* blockoff  = (int*)(p3 + (size_t)M * 8 + 256);         // 256 B

    // zero only segsum + counts; boundary u rows zeroed by k_zero_bnd;
    // empty-seg u rows masked by inv=0 in k_out3 (poison is finite)
    hipMemsetAsync(ws + o2, 0, (size_t)N * 36, stream);

    k_convert<<<512, 256, 0, stream>>>(Wq, Wk, wqkT);
    k_convC<<<512, 256, 0, stream>>>(Wv, Wout, CT);
    k_hist<<<(M + 255) / 256, 256, 0, stream>>>(index, counts, M);
    k_scan1<<<NC, 1024, 0, stream>>>(counts, starts, blocktot, N);
    k_scan2<<<1, 64, 0, stream>>>(blocktot, blockoff, NC);
    k_scan3<<<NC, 1024, 0, stream>>>(starts, cursor, blockoff, N, M);
    k_scatteridx<<<(M + 255) / 256, 256, 0, stream>>>(index, cursor, sorted, segsorted, M);
    k_zero_bnd<<<M / 64, 256, 0, stream>>>(segsorted, u, M);
    k_score_wsum<<<M / 64, 512, 0, stream>>>(msg, sorted, segsorted, wqkT, u, segsum, M);
    k_out3<<<(N + 127) / 128, 256, 0, stream>>>(u, segsum, CT, bout, out, N);
}

// Round 17
// 864.985 us; speedup vs baseline: 1.0623x; 1.0623x over previous
//
#include <hip/hip_runtime.h>
#include <hip/hip_bf16.h>

typedef _Float16 half8 __attribute__((ext_vector_type(8)));
typedef _Float16 half4 __attribute__((ext_vector_type(4)));
typedef float f32x4 __attribute__((ext_vector_type(4)));

// Geometry: D=256, H=8, A=64, M=400000 (128*3125), N=50000
// Algebra: out_g = sum_h (u_{g,h}/s_{g,h}) @ (Wv_h @ Wout_h) + bout
//          u_{g,h} = sum_{m in g} e_{m,h} * msg_m

#define MFMA16(a, b, c) __builtin_amdgcn_mfma_f32_16x16x32_f16(a, b, c, 0, 0, 0)

// ---------------- wqkT panels in FRAGMENT ORDER ----------------
__global__ void k_convert(const float* __restrict__ Wq, const float* __restrict__ Wk,
                          _Float16* __restrict__ wqkT)
{
    int gid = blockIdx.x * 256 + threadIdx.x;   // 131072
    int h = gid >> 14;
    int d = (gid >> 6) & 255;
    int a = gid & 63;
    int k0 = d >> 5, lk = (d >> 3) & 3, j = d & 7;
    int cb = a >> 4, lr = a & 15;
    int idx = ((k0 * 4 + cb) * 64 + lk * 16 + lr) * 8 + j;
    wqkT[h * 16384 + idx]       = (_Float16)Wq[gid];
    wqkT[(8 + h) * 16384 + idx] = (_Float16)Wk[gid];
}

// ---------------- CT = Wv_h @ Wout_h in FRAGMENT ORDER ----------------
__global__ void k_convC(const float* __restrict__ Wv, const float* __restrict__ Wout,
                        _Float16* __restrict__ CT)
{
    __shared__ float wv[4][64];
    int h = blockIdx.x >> 6, din0 = (blockIdx.x & 63) << 2;
    int t = threadIdx.x;
    wv[t >> 6][t & 63] = Wv[((h << 8) + din0 + (t >> 6)) * 64 + (t & 63)];
    __syncthreads();
    float s[4] = {0.f, 0.f, 0.f, 0.f};
    for (int a = 0; a < 64; ++a) {
        float wo = Wout[(h * 64 + a) * 256 + t];
        #pragma unroll
        for (int dd = 0; dd < 4; ++dd) s[dd] += wv[dd][a] * wo;
    }
    int nb = t >> 4, lr = t & 15;
    #pragma unroll
    for (int dd = 0; dd < 4; ++dd) {
        int din = din0 + dd;
        int k0 = din >> 5, lk = (din >> 3) & 3, j = din & 7;
        CT[(size_t)((nb * 8 + h) * 8 + k0) * 512 + (lk * 16 + lr) * 8 + j] = (_Float16)s[dd];
    }
}

// ---------------- counting sort ----------------
__global__ void k_hist(const int* __restrict__ index, int* __restrict__ counts, int M) {
    int m = blockIdx.x * 256 + threadIdx.x;
    if (m < M) atomicAdd(&counts[index[m]], 1);
}

__global__ __launch_bounds__(1024) void k_scan1(const int* __restrict__ counts,
                                                int* __restrict__ starts,
                                                int* __restrict__ blocktot, int N) {
    __shared__ int s[1024];
    int b = blockIdx.x, t = threadIdx.x;
    int i = b * 1024 + t;
    int x = (i < N) ? counts[i] : 0;
    s[t] = x;
    __syncthreads();
    #pragma unroll
    for (int off = 1; off < 1024; off <<= 1) {
        int v = (t >= off) ? s[t - off] : 0;
        __syncthreads();
        s[t] += v;
        __syncthreads();
    }
    if (i < N) starts[i] = s[t] - x;
    if (t == 1023) blocktot[b] = s[1023];
}

__global__ void k_scan2(const int* __restrict__ blocktot, int* __restrict__ blockoff, int NC) {
    if (threadIdx.x == 0 && blockIdx.x == 0) {
        int run = 0;
        for (int i = 0; i < NC; ++i) { blockoff[i] = run; run += blocktot[i]; }
    }
}

__global__ __launch_bounds__(1024) void k_scan3(int* __restrict__ starts,
                                                int* __restrict__ cursor,
                                                const int* __restrict__ blockoff,
                                                int N, int M) {
    int b = blockIdx.x, t = threadIdx.x;
    int i = b * 1024 + t;
    if (i < N) {
        int v = starts[i] + blockoff[b];
        starts[i] = v;
        cursor[i] = v;
    }
    if (b == 0 && t == 0) starts[N] = M;
}

__global__ void k_scatteridx(const int* __restrict__ index, int* __restrict__ cursor,
                             int* __restrict__ sorted, int* __restrict__ segsorted, int M) {
    int m = blockIdx.x * 256 + threadIdx.x;
    if (m < M) {
        int idx = index[m];
        int pos = atomicAdd(&cursor[idx], 1);
        sorted[pos] = m;
        segsorted[pos] = idx;
    }
}

// ---------------- zero u rows of block-boundary segments (128-row blocks) --------
__global__ __launch_bounds__(256) void k_zero_bnd(const int* __restrict__ segsorted,
                                                  float* __restrict__ u, int M) {
    long r0 = (long)blockIdx.x * 128;
    int g0 = segsorted[r0];
    int g1 = segsorted[r0 + 127];
    int t = threadIdx.x;
    float4 z = {0.f, 0.f, 0.f, 0.f};
    float4* p0 = (float4*)(u + (long)g0 * 2048);
    float4* p1 = (float4*)(u + (long)g1 * 2048);
    p0[t] = z; p0[t + 256] = z;
    p1[t] = z; p1[t + 256] = z;
}

// ---------------- flush helper (nt store on interior; atomics on boundary) --------
__device__ __forceinline__ void flush_u(float* __restrict__ u, float* __restrict__ segsum,
                                        int g, int gl0, int ghi, int h, int l,
                                        f32x4 a0, float se)
{
    bool bd = (g == gl0) || (g == ghi);
    float* d0 = u + (long)g * 2048 + h * 256 + l * 4;
    if (bd) {
        atomicAdd(d0 + 0, a0[0]); atomicAdd(d0 + 1, a0[1]);
        atomicAdd(d0 + 2, a0[2]); atomicAdd(d0 + 3, a0[3]);
    } else {
        __builtin_nontemporal_store(a0, (f32x4*)d0);
    }
    if (l == 0) {
        float* ds = segsum + (long)g * 8 + h;
        if (bd) atomicAdd(ds, se); else *ds = se;
    }
}

// ---------------- fused: B-in-registers scores + weighted segment-sum ----------------
// 128-row blocks, 8 waves; wave w = HEAD w over all 128 rows (2 passes of 64).
// Per (pa,cb): B chunk (bq[8]+bk[8], 64 VGPR) loaded in ONE 16-load burst, then
// 4 row tiles x 8 k0 of pure LDS+MFMA (zero global loads in the hot loop).
// B traffic: 1 MB/block (r14: 2 MB). Live regs ~110 < 128 cap -> no spill.
__global__ __launch_bounds__(512) void k_score_wsum(
    const float* __restrict__ msg, const int* __restrict__ sorted,
    const int* __restrict__ segsorted, const _Float16* __restrict__ wqkT,
    float* __restrict__ u, float* __restrict__ segsum, int M)
{
    __shared__ __align__(16) _Float16 At[128 * 256];   // 64 KB, XOR-swz row-major
    __shared__ float e_lds[128][9];                    // 4.6 KB
    __shared__ int s_id[128];
    __shared__ int s_sg[128];
    char* ldsA = (char*)At;
    const int t = threadIdx.x;

    // bijective XCD-chunked swizzle
    int nwg = gridDim.x;
    int qc = nwg >> 3, rc = nwg & 7;
    int xcd = blockIdx.x & 7, ofs = blockIdx.x >> 3;
    int blk = ((xcd < rc) ? xcd * (qc + 1) : rc * (qc + 1) + (xcd - rc) * qc) + ofs;
    const long m0 = (long)blk * 128;

    if (t < 128) {
        s_id[t] = sorted[m0 + t];
        s_sg[t] = segsorted[m0 + t];
    }
    __syncthreads();

    // stage A: gathered 128x256 f32 -> f16 LDS (swz); nt-loads keep wqkT in L2
    const f32x4* msgf4 = (const f32x4*)msg;
    #pragma unroll
    for (int it = 0; it < 16; ++it) {
        int e4 = it * 512 + t;
        int row = e4 >> 6, c4 = e4 & 63;
        f32x4 v = __builtin_nontemporal_load(msgf4 + (long)s_id[row] * 64 + c4);
        half4 hv = {(_Float16)v[0], (_Float16)v[1], (_Float16)v[2], (_Float16)v[3]};
        int bb = ((row << 9) + (c4 << 3)) ^ ((row & 7) << 4);
        *(half4*)(ldsA + bb) = hv;
    }
    __syncthreads();

    const int w = t >> 6, l = t & 63, lr = l & 15, lk = l >> 4;
    const f32x4 zero = {0.f, 0.f, 0.f, 0.f};
    const _Float16* wq = wqkT + (size_t)w * 16384;
    const _Float16* wk = wqkT + (size_t)(8 + w) * 16384;

    #pragma unroll 1
    for (int pa = 0; pa < 2; ++pa) {       // 64 rows per pass, 4 row tiles
        f32x4 p[4] = {zero, zero, zero, zero};

        #pragma unroll 1
        for (int cb = 0; cb < 4; ++cb) {
            // ---- one burst: this head's B chunk into registers (64 VGPR) ----
            half8 bq[8], bk[8];
            #pragma unroll
            for (int k0 = 0; k0 < 8; ++k0) {
                bq[k0] = *(const half8*)(wq + ((k0 * 4 + cb) * 64 + l) * 8);
                bk[k0] = *(const half8*)(wk + ((k0 * 4 + cb) * 64 + l) * 8);
            }
            // ---- 4 row tiles x 8 k0: pure LDS + MFMA ----
            #pragma unroll
            for (int rt = 0; rt < 4; ++rt) {
                const int r = pa * 64 + rt * 16 + lr;
                f32x4 aq = zero, ak = zero;
                #pragma unroll
                for (int k0 = 0; k0 < 8; ++k0) {
                    int c = k0 * 64 + lk * 16;
                    half8 a = *(const half8*)(ldsA + (((r << 9) + c) ^ ((r & 7) << 4)));
                    aq = MFMA16(a, bq[k0], aq);
                    ak = MFMA16(a, bk[k0], ak);
                }
                p[rt] += aq * ak;
            }
        }
        // butterfly over the 16-lane col group
        #pragma unroll
        for (int off = 1; off < 16; off <<= 1) {
            #pragma unroll
            for (int rt = 0; rt < 4; ++rt) {
                p[rt][0] += __shfl_xor(p[rt][0], off);
                p[rt][1] += __shfl_xor(p[rt][1], off);
                p[rt][2] += __shfl_xor(p[rt][2], off);
                p[rt][3] += __shfl_xor(p[rt][3], off);
            }
        }
        if (lr == 0) {
            #pragma unroll
            for (int rt = 0; rt < 4; ++rt) {
                int rb = pa * 64 + rt * 16 + lk * 4;
                #pragma unroll
                for (int j = 0; j < 4; ++j) {
                    float s = p[rt][j];
                    s = (s >= 0.f) ? s : 0.2f * s;
                    e_lds[rb + j][w] = __expf(s);     // |s|<~50 << 88: f32-safe
                }
            }
        }
    }
    __syncthreads();

    // ---- weighted segment-sum: wave w -> head w; lane owns 4 msg cols ----
    const int gl0 = s_sg[0], ghi = s_sg[127];
    f32x4 a0 = zero;
    float se = 0.f;
    int cur = gl0;

    #pragma unroll 4
    for (int row = 0; row < 128; ++row) {
        int sg = s_sg[row];
        if (sg != cur) {                 // wave-uniform branch
            flush_u(u, segsum, cur, gl0, ghi, w, l, a0, se);
            cur = sg; a0 = zero; se = 0.f;
        }
        int bb = ((row << 9) + (l << 3)) ^ ((row & 7) << 4);
        half4 mv = *(const half4*)(ldsA + bb);
        float e = e_lds[row][w];
        a0[0] += e * (float)mv[0];
        a0[1] += e * (float)mv[1];
        a0[2] += e * (float)mv[2];
        a0[3] += e * (float)mv[3];
        se += e;
    }
    flush_u(u, segsum, cur, gl0, ghi, w, l, a0, se);
}

// ---------------- out: barrier-free, LDS-free, 32 rows/wave ----------------
__global__ __launch_bounds__(256, 2) void k_out3(
    const float* __restrict__ u, const float* __restrict__ segsum,
    const _Float16* __restrict__ CT, const float* __restrict__ bout,
    float* __restrict__ out, int N)
{
    const int t = threadIdx.x;
    const int w = t >> 6, l = t & 63, lr = l & 15, lk = l >> 4;
    const long r0 = ((long)blockIdx.x * 4 + w) * 32;
    if (r0 >= N) return;            // no barriers: safe early exit

    const f32x4 zero = {0.f, 0.f, 0.f, 0.f};
    f32x4 ac0[16], ac1[16];
    #pragma unroll
    for (int nb = 0; nb < 16; ++nb) { ac0[nb] = zero; ac1[nb] = zero; }

    long rlo = r0 + lr;      if (rlo > N - 1) rlo = N - 1;   // clamp reads
    long rhi = r0 + 16 + lr; if (rhi > N - 1) rhi = N - 1;
    const float* ulo = u + rlo * 2048;
    const float* uhi = u + rhi * 2048;
    const float* sslo = segsum + rlo * 8;
    const float* sshi = segsum + rhi * 8;

    #pragma unroll 1
    for (int kc = 0; kc < 8; ++kc) {
        float s0 = sslo[kc];
        float i0 = (s0 > 0.f) ? 1.f / s0 : 0.f;
        float s1 = sshi[kc];
        float i1 = (s1 > 0.f) ? 1.f / s1 : 0.f;
        #pragma unroll
        for (int k0 = 0; k0 < 8; ++k0) {
            const f32x4* p0 = (const f32x4*)(ulo + kc * 256 + k0 * 32 + lk * 8);
            const f32x4* p1 = (const f32x4*)(uhi + kc * 256 + k0 * 32 + lk * 8);
            f32x4 ua = __builtin_nontemporal_load(p0);
            f32x4 ub = __builtin_nontemporal_load(p0 + 1);
            f32x4 uc = __builtin_nontemporal_load(p1);
            f32x4 ud = __builtin_nontemporal_load(p1 + 1);
            half8 alo = {(_Float16)(ua[0] * i0), (_Float16)(ua[1] * i0),
                         (_Float16)(ua[2] * i0), (_Float16)(ua[3] * i0),
                         (_Float16)(ub[0] * i0), (_Float16)(ub[1] * i0),
                         (_Float16)(ub[2] * i0), (_Float16)(ub[3] * i0)};
            half8 ahi = {(_Float16)(uc[0] * i1), (_Float16)(uc[1] * i1),
                         (_Float16)(uc[2] * i1), (_Float16)(uc[3] * i1),
                         (_Float16)(ud[0] * i1), (_Float16)(ud[1] * i1),
                         (_Float16)(ud[2] * i1), (_Float16)(ud[3] * i1)};
            #pragma unroll
            for (int nb = 0; nb < 16; ++nb) {
                half8 b = *(const half8*)(CT + (size_t)((nb * 8 + kc) * 8 + k0) * 512 + l * 8);
                ac0[nb] = MFMA16(alo, b, ac0[nb]);
                ac1[nb] = MFMA16(ahi, b, ac1[nb]);
            }
        }
    }

    #pragma unroll
    for (int nb = 0; nb < 16; ++nb) {
        int col = nb * 16 + lr;
        float bb = bout[col];
        #pragma unroll
        for (int j = 0; j < 4; ++j) {
            long row = r0 + lk * 4 + j;
            if (row < N) out[row * 256 + col] = ac0[nb][j] + bb;
            long row2 = r0 + 16 + lk * 4 + j;
            if (row2 < N) out[row2 * 256 + col] = ac1[nb][j] + bb;
        }
    }
}

extern "C" void kernel_launch(void* const* d_in, const int* in_sizes, int n_in,
                              void* d_out, int out_size, void* d_ws, size_t ws_size,
                              hipStream_t stream)
{
    const float* msg   = (const float*)d_in[0];
    const int*   index = (const int*)d_in[1];
    const float* Wq    = (const float*)d_in[4];
    const float* Wk    = (const float*)d_in[5];
    const float* Wv    = (const float*)d_in[6];
    const float* Wout  = (const float*)d_in[7];
    const float* bout  = (const float*)d_in[8];
    float* out = (float*)d_out;

    const int M = in_sizes[0] / 256;   // 400000
    const int N = out_size / 256;      // 50000
    const int NC = (N + 1023) / 1024;  // 49 scan chunks

    char* ws = (char*)d_ws;
    _Float16* wqkT = (_Float16*)(ws);              // 524288 B
    _Float16* CT   = (_Float16*)(ws + 524288);     // 1048576 B
    size_t o2 = 1572864;
    float* segsum = (float*)(ws + o2);                         // N*32
    int* counts   = (int*)(ws + o2 + (size_t)N * 32);          // N*4
    size_t uoff   = (o2 + (size_t)N * 36 + 255) & ~(size_t)255;
    float* u      = (float*)(ws + uoff);                       // N*8192
    size_t p2     = uoff + (size_t)N * 8192;
    int* cursor    = (int*)(ws + p2);                          // N*4
    int* starts    = (int*)(ws + p2 + (size_t)N * 4);          // (N+1)*4
    char* p3       = ws + p2 + (((size_t)N * 8 + 4 + 63) & ~(size_t)63);
    int* sorted    = (int*)(p3);                               // M*4
    int* segsorted = (int*)(p3 + (size_t)M * 4);               // M*4
    int* blocktot  = (int*)(p3 + (size_t)M * 8);               // 256 B
    int* blockoff  = (int*)(p3 + (size_t)M * 8 + 256);         // 256 B

    // zero only segsum + counts; boundary u rows zeroed by k_zero_bnd;
    // empty-seg u rows masked by inv=0 in k_out3 (poison is finite)
    hipMemsetAsync(ws + o2, 0, (size_t)N * 36, stream);

    k_convert<<<512, 256, 0, stream>>>(Wq, Wk, wqkT);
    k_convC<<<512, 256, 0, stream>>>(Wv, Wout, CT);
    k_hist<<<(M + 255) / 256, 256, 0, stream>>>(index, counts, M);
    k_scan1<<<NC, 1024, 0, stream>>>(counts, starts, blocktot, N);
    k_scan2<<<1, 64, 0, stream>>>(blocktot, blockoff, NC);
    k_scan3<<<NC, 1024, 0, stream>>>(starts, cursor, blockoff, N, M);
    k_scatteridx<<<(M + 255) / 256, 256, 0, stream>>>(index, cursor, sorted, segsorted, M);
    k_zero_bnd<<<M / 128, 256, 0, stream>>>(segsorted, u, M);
    k_score_wsum<<<M / 128, 512, 0, stream>>>(msg, sorted, segsorted, wqkT, u, segsum, M);
    k_out3<<<(N + 127) / 128, 256, 0, stream>>>(u, segsum, CT, bout, out, N);
}

// Round 18
// 777.034 us; speedup vs baseline: 1.1826x; 1.1132x over previous
//
#include <hip/hip_runtime.h>
#include <hip/hip_bf16.h>

typedef _Float16 half8 __attribute__((ext_vector_type(8)));
typedef _Float16 half4 __attribute__((ext_vector_type(4)));
typedef float f32x4 __attribute__((ext_vector_type(4)));

// Geometry: D=256, H=8, A=64, M=400000 (128*3125), N=50000
// Algebra: out_g = sum_h (u_{g,h}/s_{g,h}) @ (Wv_h @ Wout_h) + bout
//          u_{g,h} = sum_{m in g} e_{m,h} * msg_m

#define MFMA16(a, b, c) __builtin_amdgcn_mfma_f32_16x16x32_f16(a, b, c, 0, 0, 0)

// ---------------- fused prep: wqkT convert + CT build + histogram ----------------
// blocks 0..511: wqkT fragment-order convert; 512..1023: CT = Wv@Wout fragment-order;
// 1024..: histogram of index.
__global__ void k_prep(const float* __restrict__ Wq, const float* __restrict__ Wk,
                       const float* __restrict__ Wv, const float* __restrict__ Wout,
                       _Float16* __restrict__ wqkT, _Float16* __restrict__ CT,
                       const int* __restrict__ index, int* __restrict__ counts, int M)
{
    const int b = blockIdx.x;
    const int t = threadIdx.x;
    if (b < 512) {
        int gid = b * 256 + t;   // 131072
        int h = gid >> 14;
        int d = (gid >> 6) & 255;
        int a = gid & 63;
        int k0 = d >> 5, lk = (d >> 3) & 3, j = d & 7;
        int cb = a >> 4, lr = a & 15;
        int idx = ((k0 * 4 + cb) * 64 + lk * 16 + lr) * 8 + j;
        wqkT[h * 16384 + idx]       = (_Float16)Wq[gid];
        wqkT[(8 + h) * 16384 + idx] = (_Float16)Wk[gid];
    } else if (b < 1024) {
        __shared__ float wv[4][64];
        int bb = b - 512;
        int h = bb >> 6, din0 = (bb & 63) << 2;
        wv[t >> 6][t & 63] = Wv[((h << 8) + din0 + (t >> 6)) * 64 + (t & 63)];
        __syncthreads();
        float s[4] = {0.f, 0.f, 0.f, 0.f};
        for (int a = 0; a < 64; ++a) {
            float wo = Wout[(h * 64 + a) * 256 + t];
            #pragma unroll
            for (int dd = 0; dd < 4; ++dd) s[dd] += wv[dd][a] * wo;
        }
        int nb = t >> 4, lr = t & 15;
        #pragma unroll
        for (int dd = 0; dd < 4; ++dd) {
            int din = din0 + dd;
            int k0 = din >> 5, lk = (din >> 3) & 3, j = din & 7;
            CT[(size_t)((nb * 8 + h) * 8 + k0) * 512 + (lk * 16 + lr) * 8 + j] = (_Float16)s[dd];
        }
    } else {
        int m = (b - 1024) * 256 + t;
        if (m < M) atomicAdd(&counts[index[m]], 1);
    }
}

// ---------------- counting sort ----------------
__global__ __launch_bounds__(1024) void k_scan1(const int* __restrict__ counts,
                                                int* __restrict__ starts,
                                                int* __restrict__ blocktot, int N) {
    __shared__ int s[1024];
    int b = blockIdx.x, t = threadIdx.x;
    int i = b * 1024 + t;
    int x = (i < N) ? counts[i] : 0;
    s[t] = x;
    __syncthreads();
    #pragma unroll
    for (int off = 1; off < 1024; off <<= 1) {
        int v = (t >= off) ? s[t - off] : 0;
        __syncthreads();
        s[t] += v;
        __syncthreads();
    }
    if (i < N) starts[i] = s[t] - x;
    if (t == 1023) blocktot[b] = s[1023];
}

__global__ void k_scan2(const int* __restrict__ blocktot, int* __restrict__ blockoff, int NC) {
    if (threadIdx.x == 0 && blockIdx.x == 0) {
        int run = 0;
        for (int i = 0; i < NC; ++i) { blockoff[i] = run; run += blocktot[i]; }
    }
}

__global__ __launch_bounds__(1024) void k_scan3(int* __restrict__ starts,
                                                int* __restrict__ cursor,
                                                const int* __restrict__ blockoff,
                                                int N, int M) {
    int b = blockIdx.x, t = threadIdx.x;
    int i = b * 1024 + t;
    if (i < N) {
        int v = starts[i] + blockoff[b];
        starts[i] = v;
        cursor[i] = v;
    }
    if (b == 0 && t == 0) starts[N] = M;
}

__global__ void k_scatteridx(const int* __restrict__ index, int* __restrict__ cursor,
                             int* __restrict__ sorted, int* __restrict__ segsorted, int M) {
    int m = blockIdx.x * 256 + threadIdx.x;
    if (m < M) {
        int idx = index[m];
        int pos = atomicAdd(&cursor[idx], 1);
        sorted[pos] = m;
        segsorted[pos] = idx;
    }
}

// ---------------- zero u rows of block-boundary segments (128-row blocks) --------
__global__ __launch_bounds__(256) void k_zero_bnd(const int* __restrict__ segsorted,
                                                  float* __restrict__ u, int M) {
    long r0 = (long)blockIdx.x * 128;
    int g0 = segsorted[r0];
    int g1 = segsorted[r0 + 127];
    int t = threadIdx.x;
    float4 z = {0.f, 0.f, 0.f, 0.f};
    float4* p0 = (float4*)(u + (long)g0 * 2048);
    float4* p1 = (float4*)(u + (long)g1 * 2048);
    p0[t] = z; p0[t + 256] = z;
    p1[t] = z; p1[t + 256] = z;
}

// ---------------- flush helper (nt store on interior; atomics on boundary) --------
__device__ __forceinline__ void flush_u(float* __restrict__ u, float* __restrict__ segsum,
                                        int g, int gl0, int ghi, int h, int l,
                                        f32x4 a0, float se)
{
    bool bd = (g == gl0) || (g == ghi);
    float* d0 = u + (long)g * 2048 + h * 256 + l * 4;
    if (bd) {
        atomicAdd(d0 + 0, a0[0]); atomicAdd(d0 + 1, a0[1]);
        atomicAdd(d0 + 2, a0[2]); atomicAdd(d0 + 3, a0[3]);
    } else {
        __builtin_nontemporal_store(a0, (f32x4*)d0);
    }
    if (l == 0) {
        float* ds = segsum + (long)g * 8 + h;
        if (bd) atomicAdd(ds, se); else *ds = se;
    }
}

// ---------------- fused: barrier-free scores + weighted segment-sum ----------------
// r14's best-measured structure (VGPR 64, 2 blocks/CU): wave w -> row-half rh=w&1,
// heads {w>>1,(w>>1)+4}; 6 f32x4 live in inner loop; + s_setprio around MFMA region.
__global__ __launch_bounds__(512) void k_score_wsum(
    const float* __restrict__ msg, const int* __restrict__ sorted,
    const int* __restrict__ segsorted, const _Float16* __restrict__ wqkT,
    float* __restrict__ u, float* __restrict__ segsum, int M)
{
    __shared__ __align__(16) _Float16 At[128 * 256];   // 64 KB, XOR-swz row-major
    __shared__ float e_lds[128][9];                    // 4.6 KB
    __shared__ int s_id[128];
    __shared__ int s_sg[128];
    char* ldsA = (char*)At;
    const int t = threadIdx.x;

    // bijective XCD-chunked swizzle
    int nwg = gridDim.x;
    int qc = nwg >> 3, rc = nwg & 7;
    int xcd = blockIdx.x & 7, ofs = blockIdx.x >> 3;
    int blk = ((xcd < rc) ? xcd * (qc + 1) : rc * (qc + 1) + (xcd - rc) * qc) + ofs;
    const long m0 = (long)blk * 128;

    if (t < 128) {
        s_id[t] = sorted[m0 + t];
        s_sg[t] = segsorted[m0 + t];
    }
    __syncthreads();

    // stage A: gathered 128x256 f32 -> f16 LDS (swz); nt-loads keep wqkT in L2
    const f32x4* msgf4 = (const f32x4*)msg;
    #pragma unroll
    for (int it = 0; it < 16; ++it) {
        int e4 = it * 512 + t;
        int row = e4 >> 6, c4 = e4 & 63;
        f32x4 v = __builtin_nontemporal_load(msgf4 + (long)s_id[row] * 64 + c4);
        half4 hv = {(_Float16)v[0], (_Float16)v[1], (_Float16)v[2], (_Float16)v[3]};
        int bb = ((row << 9) + (c4 << 3)) ^ ((row & 7) << 4);
        *(half4*)(ldsA + bb) = hv;
    }
    __syncthreads();

    const int w = t >> 6, l = t & 63, lr = l & 15, lk = l >> 4;
    const int rh = w & 1;     // row half
    const int hp = w >> 1;    // heads hp, hp+4
    const f32x4 zero = {0.f, 0.f, 0.f, 0.f};

    #pragma unroll 1
    for (int hh = 0; hh < 2; ++hh) {
        const int h = hp + hh * 4;
        const _Float16* wq = wqkT + (size_t)h * 16384;
        const _Float16* wk = wqkT + (size_t)(8 + h) * 16384;

        #pragma unroll 1
        for (int pa = 0; pa < 2; ++pa) {       // 32 rows per pass
            const int r0 = rh * 64 + pa * 32 + lr;
            const int r1 = r0 + 16;
            f32x4 pq0 = zero, pq1 = zero;
            __builtin_amdgcn_s_setprio(1);
            #pragma unroll 1
            for (int cb = 0; cb < 4; ++cb) {
                f32x4 aq0 = zero, aq1 = zero, ak0 = zero, ak1 = zero;
                #pragma unroll
                for (int k0 = 0; k0 < 8; ++k0) {
                    int c = k0 * 64 + lk * 16;
                    half8 a0 = *(const half8*)(ldsA + (((r0 << 9) + c) ^ ((r0 & 7) << 4)));
                    half8 a1 = *(const half8*)(ldsA + (((r1 << 9) + c) ^ ((r1 & 7) << 4)));
                    half8 bq = *(const half8*)(wq + ((k0 * 4 + cb) * 64 + l) * 8);
                    half8 bk = *(const half8*)(wk + ((k0 * 4 + cb) * 64 + l) * 8);
                    aq0 = MFMA16(a0, bq, aq0);
                    ak0 = MFMA16(a0, bk, ak0);
                    aq1 = MFMA16(a1, bq, aq1);
                    ak1 = MFMA16(a1, bk, ak1);
                }
                pq0 += aq0 * ak0;
                pq1 += aq1 * ak1;
            }
            __builtin_amdgcn_s_setprio(0);
            // butterfly over the 16-lane col group
            #pragma unroll
            for (int off = 1; off < 16; off <<= 1) {
                pq0[0] += __shfl_xor(pq0[0], off); pq0[1] += __shfl_xor(pq0[1], off);
                pq0[2] += __shfl_xor(pq0[2], off); pq0[3] += __shfl_xor(pq0[3], off);
                pq1[0] += __shfl_xor(pq1[0], off); pq1[1] += __shfl_xor(pq1[1], off);
                pq1[2] += __shfl_xor(pq1[2], off); pq1[3] += __shfl_xor(pq1[3], off);
            }
            if (lr == 0) {
                int rb = rh * 64 + pa * 32 + lk * 4;
                #pragma unroll
                for (int j = 0; j < 4; ++j) {
                    float s0 = pq0[j];
                    s0 = (s0 >= 0.f) ? s0 : 0.2f * s0;
                    e_lds[rb + j][h] = __expf(s0);         // |s|<~50 << 88
                    float s1 = pq1[j];
                    s1 = (s1 >= 0.f) ? s1 : 0.2f * s1;
                    e_lds[rb + 16 + j][h] = __expf(s1);
                }
            }
        }
    }
    __syncthreads();

    // ---- weighted segment-sum: wave w -> head w; lane owns 4 msg cols ----
    const int gl0 = s_sg[0], ghi = s_sg[127];
    f32x4 a0 = zero;
    float se = 0.f;
    int cur = gl0;

    #pragma unroll 4
    for (int row = 0; row < 128; ++row) {
        int sg = s_sg[row];
        if (sg != cur) {                 // wave-uniform branch
            flush_u(u, segsum, cur, gl0, ghi, w, l, a0, se);
            cur = sg; a0 = zero; se = 0.f;
        }
        int bb = ((row << 9) + (l << 3)) ^ ((row & 7) << 4);
        half4 mv = *(const half4*)(ldsA + bb);
        float e = e_lds[row][w];
        a0[0] += e * (float)mv[0];
        a0[1] += e * (float)mv[1];
        a0[2] += e * (float)mv[2];
        a0[3] += e * (float)mv[3];
        se += e;
    }
    flush_u(u, segsum, cur, gl0, ghi, w, l, a0, se);
}

// ---------------- out: barrier-free, LDS-free, 32 rows/wave ----------------
__global__ __launch_bounds__(256, 2) void k_out3(
    const float* __restrict__ u, const float* __restrict__ segsum,
    const _Float16* __restrict__ CT, const float* __restrict__ bout,
    float* __restrict__ out, int N)
{
    const int t = threadIdx.x;
    const int w = t >> 6, l = t & 63, lr = l & 15, lk = l >> 4;
    const long r0 = ((long)blockIdx.x * 4 + w) * 32;
    if (r0 >= N) return;            // no barriers: safe early exit

    const f32x4 zero = {0.f, 0.f, 0.f, 0.f};
    f32x4 ac0[16], ac1[16];
    #pragma unroll
    for (int nb = 0; nb < 16; ++nb) { ac0[nb] = zero; ac1[nb] = zero; }

    long rlo = r0 + lr;      if (rlo > N - 1) rlo = N - 1;   // clamp reads
    long rhi = r0 + 16 + lr; if (rhi > N - 1) rhi = N - 1;
    const float* ulo = u + rlo * 2048;
    const float* uhi = u + rhi * 2048;
    const float* sslo = segsum + rlo * 8;
    const float* sshi = segsum + rhi * 8;

    #pragma unroll 1
    for (int kc = 0; kc < 8; ++kc) {
        float s0 = sslo[kc];
        float i0 = (s0 > 0.f) ? 1.f / s0 : 0.f;
        float s1 = sshi[kc];
        float i1 = (s1 > 0.f) ? 1.f / s1 : 0.f;
        #pragma unroll
        for (int k0 = 0; k0 < 8; ++k0) {
            const f32x4* p0 = (const f32x4*)(ulo + kc * 256 + k0 * 32 + lk * 8);
            const f32x4* p1 = (const f32x4*)(uhi + kc * 256 + k0 * 32 + lk * 8);
            f32x4 ua = __builtin_nontemporal_load(p0);
            f32x4 ub = __builtin_nontemporal_load(p0 + 1);
            f32x4 uc = __builtin_nontemporal_load(p1);
            f32x4 ud = __builtin_nontemporal_load(p1 + 1);
            half8 alo = {(_Float16)(ua[0] * i0), (_Float16)(ua[1] * i0),
                         (_Float16)(ua[2] * i0), (_Float16)(ua[3] * i0),
                         (_Float16)(ub[0] * i0), (_Float16)(ub[1] * i0),
                         (_Float16)(ub[2] * i0), (_Float16)(ub[3] * i0)};
            half8 ahi = {(_Float16)(uc[0] * i1), (_Float16)(uc[1] * i1),
                         (_Float16)(uc[2] * i1), (_Float16)(uc[3] * i1),
                         (_Float16)(ud[0] * i1), (_Float16)(ud[1] * i1),
                         (_Float16)(ud[2] * i1), (_Float16)(ud[3] * i1)};
            __builtin_amdgcn_s_setprio(1);
            #pragma unroll
            for (int nb = 0; nb < 16; ++nb) {
                half8 b = *(const half8*)(CT + (size_t)((nb * 8 + kc) * 8 + k0) * 512 + l * 8);
                ac0[nb] = MFMA16(alo, b, ac0[nb]);
                ac1[nb] = MFMA16(ahi, b, ac1[nb]);
            }
            __builtin_amdgcn_s_setprio(0);
        }
    }

    #pragma unroll
    for (int nb = 0; nb < 16; ++nb) {
        int col = nb * 16 + lr;
        float bb = bout[col];
        #pragma unroll
        for (int j = 0; j < 4; ++j) {
            long row = r0 + lk * 4 + j;
            if (row < N) out[row * 256 + col] = ac0[nb][j] + bb;
            long row2 = r0 + 16 + lk * 4 + j;
            if (row2 < N) out[row2 * 256 + col] = ac1[nb][j] + bb;
        }
    }
}

extern "C" void kernel_launch(void* const* d_in, const int* in_sizes, int n_in,
                              void* d_out, int out_size, void* d_ws, size_t ws_size,
                              hipStream_t stream)
{
    const float* msg   = (const float*)d_in[0];
    const int*   index = (const int*)d_in[1];
    const float* Wq    = (const float*)d_in[4];
    const float* Wk    = (const float*)d_in[5];
    const float* Wv    = (const float*)d_in[6];
    const float* Wout  = (const float*)d_in[7];
    const float* bout  = (const float*)d_in[8];
    float* out = (float*)d_out;

    const int M = in_sizes[0] / 256;   // 400000
    const int N = out_size / 256;      // 50000
    const int NC = (N + 1023) / 1024;  // 49 scan chunks

    char* ws = (char*)d_ws;
    _Float16* wqkT = (_Float16*)(ws);              // 524288 B
    _Float16* CT   = (_Float16*)(ws + 524288);     // 1048576 B
    size_t o2 = 1572864;
    float* segsum = (float*)(ws + o2);                         // N*32
    int* counts   = (int*)(ws + o2 + (size_t)N * 32);          // N*4
    size_t uoff   = (o2 + (size_t)N * 36 + 255) & ~(size_t)255;
    float* u      = (float*)(ws + uoff);                       // N*8192
    size_t p2     = uoff + (size_t)N * 8192;
    int* cursor    = (int*)(ws + p2);                          // N*4
    int* starts    = (int*)(ws + p2 + (size_t)N * 4);          // (N+1)*4
    char* p3       = ws + p2 + (((size_t)N * 8 + 4 + 63) & ~(size_t)63);
    int* sorted    = (int*)(p3);                               // M*4
    int* segsorted = (int*)(p3 + (size_t)M * 4);               // M*4
    int* blocktot  = (int*)(p3 + (size_t)M * 8);               // 256 B
    int* blockoff  = (int*)(p3 + (size_t)M * 8 + 256);         // 256 B

    // zero only segsum + counts; boundary u rows zeroed by k_zero_bnd;
    // empty-seg u rows masked by inv=0 in k_out3 (poison is finite)
    hipMemsetAsync(ws + o2, 0, (size_t)N * 36, stream);

    k_prep<<<1024 + (M + 255) / 256, 256, 0, stream>>>(Wq, Wk, Wv, Wout, wqkT, CT,
                                                       index, counts, M);
    k_scan1<<<NC, 1024, 0, stream>>>(counts, starts, blocktot, N);
    k_scan2<<<1, 64, 0, stream>>>(blocktot, blockoff, NC);
    k_scan3<<<NC, 1024, 0, stream>>>(starts, cursor, blockoff, N, M);
    k_scatteridx<<<(M + 255) / 256, 256, 0, stream>>>(index, cursor, sorted, segsorted, M);
    k_zero_bnd<<<M / 128, 256, 0, stream>>>(segsorted, u, M);
    k_score_wsum<<<M / 128, 512, 0, stream>>>(msg, sorted, segsorted, wqkT, u, segsum, M);
    k_out3<<<(N + 127) / 128, 256, 0, stream>>>(u, segsum, CT, bout, out, N);
}